// Round 2
// baseline (1411.238 us; speedup 1.0000x reference)
//
#include <hip/hip_runtime.h>

// Problem constants (from reference)
constexpr int B_ = 8;
constexpr int N_ = 16384;
constexpr int NG = 512;     // NUM_GROUPS
constexpr int GS = 32;      // GROUP_SIZE
constexpr int KORIG = 160;  // K_ORIGINAL = 5*GROUP_SIZE
constexpr int P_ = 32;      // FPS blocks per batch (one wave each)
constexpr int SLICE = N_ / P_;        // 512 points per block
constexpr int PTS = SLICE / 64;       // 8 points per lane, lane-major (tie-break order!)
#define R2 0.04f
#define RADIUS 0.2f

__device__ __forceinline__ unsigned f32_ord(float f) {
  unsigned u = __float_as_uint(f);
  return (u & 0x80000000u) ? ~u : (u | 0x80000000u);
}

// slots[b][parity][blk]: tag(18b)<<46 | ord(dist)(32b)<<14 | (16383-gidx)(14b)
__global__ void fps_init_kernel(unsigned long long* slots) {
  slots[threadIdx.x] = ~0ull;  // tag 0x3FFFF never matches any k<511
}

// ---------------- Kernel 1: distributed FPS with dataflow sync ----------------
// 32 one-wave blocks per batch; cross-block argmax via tagged agent-scope atomics.
// Parity double-buffer: a block can be at most 1 iteration ahead of any reader,
// and iterations k, k+2 use the same slot only after all readers consumed k.
// Stale values from a previous graph replay are bit-identical (deterministic), benign.
__global__ __launch_bounds__(64) void fps_kernel(const float4* __restrict__ p4,
                                                 const int* __restrict__ lengths,
                                                 float* __restrict__ centers,
                                                 unsigned long long* __restrict__ slots) {
#pragma clang fp contract(off)
  const int b = blockIdx.x & 7;     // batch round-robins over XCDs
  const int blk = blockIdx.x >> 3;  // 0..31
  const int lane = threadIdx.x;
  const int len = lengths[b];
  const float4* bp = p4 + (size_t)b * N_;
  const int lbase = blk * SLICE + lane * PTS;  // lane-major: lane order == index order

  float x[PTS], y[PTS], z[PTS], mind[PTS];
#pragma unroll
  for (int j = 0; j < PTS; ++j) {
    float4 p = bp[lbase + j];
    x[j] = p.x; y[j] = p.y; z[j] = p.z;
    mind[j] = (lbase + j < len) ? __builtin_inff() : -__builtin_inff();
  }

  float4 c0 = bp[0];  // reference scan starts at cur=0
  float cx = c0.x, cy = c0.y, cz = c0.z;
  if (blk == 0 && lane == 0) {
    size_t o = (size_t)b * NG * 3;
    centers[o] = cx; centers[o + 1] = cy; centers[o + 2] = cz;
  }

  unsigned long long* const batch_slots = slots + (size_t)b * 2 * P_;

  for (int k = 0; k < NG - 1; ++k) {
    // update mindist + per-lane argmax (strict > keeps first index within lane)
    float bd = -__builtin_inff();
    int bj = 0;
#pragma unroll
    for (int j = 0; j < PTS; ++j) {
      float dx = x[j] - cx;
      float dy = y[j] - cy;
      float dz = z[j] - cz;
      float d = dx * dx + dy * dy + dz * dz;  // contract OFF: exact reference rounding
      float m = fminf(mind[j], d);
      mind[j] = m;
      if (m > bd) { bd = m; bj = j; }
    }
    // wave max on 32-bit float, then first-lane tie-break via ballot
    float wmax = bd;
#pragma unroll
    for (int off = 32; off; off >>= 1) wmax = fmaxf(wmax, __shfl_xor(wmax, off, 64));
    unsigned long long eq = __ballot(bd == wmax);
    int wl = __ffsll(eq) - 1;            // lowest lane == lowest global index
    int wj = __shfl(bj, wl, 64);
    int gidx = blk * SLICE + wl * PTS + wj;

    unsigned long long* slotbuf = batch_slots + (k & 1) * P_;
    if (lane == 0) {
      unsigned long long val = ((unsigned long long)k << 46) |
                               ((unsigned long long)f32_ord(wmax) << 14) |
                               (unsigned long long)(16383 - gidx);
      __hip_atomic_store(&slotbuf[blk], val, __ATOMIC_RELAXED, __HIP_MEMORY_SCOPE_AGENT);
    }
    // spin until all 32 partials for iteration k are published
    unsigned long long myv = 0;
    const bool need = lane < P_;
    for (;;) {
      if (need) myv = __hip_atomic_load(&slotbuf[lane], __ATOMIC_RELAXED,
                                        __HIP_MEMORY_SCOPE_AGENT);
      bool ok = !need || ((int)(myv >> 46) == k);
      if (__all(ok)) break;
    }
    // global argmax: tags equal, payload = (ord, ~gidx) -> max == first-index argmax
    unsigned long long kk = need ? myv : 0ull;
#pragma unroll
    for (int off = 32; off; off >>= 1) {
      unsigned long long o = __shfl_xor(kk, off, 64);
      if (o > kk) kk = o;
    }
    int nxt = 16383 - (int)(kk & 0x3FFFull);
    float4 c = bp[nxt];  // read-only input: safe redundant load, L2-hot
    cx = c.x; cy = c.y; cz = c.z;
    if (blk == 0 && lane == 0) {
      size_t o = ((size_t)b * NG + (k + 1)) * 3;
      centers[o] = cx; centers[o + 1] = cy; centers[o + 2] = cz;
    }
  }
}

// ---------------- Kernel 2: ball query + energy top-k + gather ----------------
// One wave per (batch, group). Ordered compaction of first 160 in-ball indices,
// then 32 rounds of min-key extraction = top_k by (energy desc, index asc).
__global__ __launch_bounds__(64) void group_kernel(const float4* __restrict__ p4,
                                                   const int* __restrict__ lengths,
                                                   const float* __restrict__ centers,
                                                   float4* __restrict__ outg) {
#pragma clang fp contract(off)
  const int gid = blockIdx.x;
  const int b = gid >> 9;
  const int lane = threadIdx.x;
  const int len = lengths[b];
  const float4* bp = p4 + (size_t)b * N_;
  const float cx = centers[(size_t)gid * 3 + 0];
  const float cy = centers[(size_t)gid * 3 + 1];
  const float cz = centers[(size_t)gid * 3 + 2];

  __shared__ int cand[KORIG];
  int M = 0;  // wave-uniform running in-ball count
  for (int cb = 0; cb < N_ && M < KORIG; cb += 256) {
#pragma unroll
    for (int q = 0; q < 4; ++q) {
      const int i = cb + q * 64 + lane;
      float4 p = bp[i];
      float dx = p.x - cx;
      float dy = p.y - cy;
      float dz = p.z - cz;
      float d2 = dx * dx + dy * dy + dz * dz;  // contract OFF
      const bool pred = (i < len) && (d2 < R2);
      unsigned long long mb = __ballot(pred);
      if (pred) {
        int pos = M + (int)__popcll(mb & ((1ull << lane) - 1ull));
        if (pos < KORIG) cand[pos] = i;  // first-160-by-index semantics
      }
      M += (int)__popcll(mb);
    }
  }
  if (M > KORIG) M = KORIG;
  __syncthreads();

  // keys: (energy desc, index asc) -> ascending u64
  const unsigned long long SENT = ~0ull;
  unsigned long long key0 = SENT, key1 = SENT, key2 = SENT;
  {
    int c0 = lane, c1 = lane + 64, c2 = lane + 128;
    if (c0 < M) { int i = cand[c0]; key0 = ((unsigned long long)(~f32_ord(bp[i].w)) << 32) | (unsigned)i; }
    if (c1 < M) { int i = cand[c1]; key1 = ((unsigned long long)(~f32_ord(bp[i].w)) << 32) | (unsigned)i; }
    if (c2 < M) { int i = cand[c2]; key2 = ((unsigned long long)(~f32_ord(bp[i].w)) << 32) | (unsigned)i; }
  }

  int mysel = -1;  // lane j holds the j-th selected index
  for (int j = 0; j < GS; ++j) {
    unsigned long long kmin = key0 < key1 ? key0 : key1;
    if (key2 < kmin) kmin = key2;
#pragma unroll
    for (int off = 32; off > 0; off >>= 1) {
      unsigned long long o = __shfl_xor(kmin, off, 64);
      if (o < kmin) kmin = o;
    }
    if (kmin == SENT) break;  // fewer than 32 candidates; rest stay -1
    if (lane == j) mysel = (int)(unsigned)kmin;
    if (key0 == kmin) key0 = SENT;
    if (key1 == kmin) key1 = SENT;
    if (key2 == kmin) key2 = SENT;
  }

  const int first = __shfl(mysel, 0, 64);  // highest-energy candidate (or -1 if empty)
  if (lane < GS) {
    int idx = (mysel < 0) ? first : mysel;  // reference: -1 -> idx[:, :, :1]
    float4 o;
    if (idx >= 0) {
      float4 p = bp[idx];
      o.x = (p.x - cx) / RADIUS;
      o.y = (p.y - cy) / RADIUS;
      o.z = (p.z - cz) / RADIUS;
      o.w = p.w / RADIUS;
    } else {
      // masked_gather gives 0, then (0 - center)/radius
      o.x = (0.0f - cx) / RADIUS;
      o.y = (0.0f - cy) / RADIUS;
      o.z = (0.0f - cz) / RADIUS;
      o.w = 0.0f;
    }
    outg[(size_t)gid * GS + lane] = o;
  }
}

extern "C" void kernel_launch(void* const* d_in, const int* in_sizes, int n_in,
                              void* d_out, int out_size, void* d_ws, size_t ws_size,
                              hipStream_t stream) {
  const float4* pts = (const float4*)d_in[0];
  const int* lengths = (const int*)d_in[1];
  float* out = (float*)d_out;
  // out layout: groups (8,512,32,4) flat, then centers (8,512,3) flat
  float* centers = out + (size_t)B_ * NG * GS * 4;
  float4* groups = (float4*)out;
  unsigned long long* slots = (unsigned long long*)d_ws;  // 8*2*32*8B = 4 KB

  fps_init_kernel<<<1, B_ * 2 * P_, 0, stream>>>(slots);
  fps_kernel<<<B_ * P_, 64, 0, stream>>>(pts, lengths, centers, slots);
  group_kernel<<<B_ * NG, 64, 0, stream>>>(pts, lengths, centers, groups);
}

// Round 3
// 1195.770 us; speedup vs baseline: 1.1802x; 1.1802x over previous
//
#include <hip/hip_runtime.h>

// Problem constants (from reference)
constexpr int B_ = 8;
constexpr int N_ = 16384;
constexpr int NG = 512;     // NUM_GROUPS
constexpr int GS = 32;      // GROUP_SIZE
constexpr int KORIG = 160;  // K_ORIGINAL = 5*GROUP_SIZE
#define R2 0.04f
#define RADIUS 0.2f

__device__ __forceinline__ unsigned f32_ord(float f) {
  unsigned u = __float_as_uint(f);
  return (u & 0x80000000u) ? ~u : (u | 0x80000000u);
}

// ---------------- Kernel 1: farthest point sampling ----------------
// One block per batch, 1024 threads, CONTIGUOUS layout: thread t owns points
// [16t, 16t+16). Then index order == (wave, lane, j) order, so first-index
// argmax tie-break = lowest wave, lowest lane, lowest j. All reduces are
// 32-bit f32 max (exact, order-free); ties resolved by ballot+ffs.
// One barrier per iteration; publish slots parity-double-buffered.
__global__ __launch_bounds__(1024) void fps_kernel(const float4* __restrict__ p4,
                                                   const int* __restrict__ lengths,
                                                   float* __restrict__ centers) {
#pragma clang fp contract(off)
  const int b = blockIdx.x;
  const int t = threadIdx.x;
  const int lane = t & 63;
  const int len = lengths[b];
  const float4* bp = p4 + (size_t)b * N_;

  __shared__ float4 s_pub[2][16];  // {x, y, z, wavemax} per wave, parity dbuf

  float x[16], y[16], z[16], m[16];
#pragma unroll
  for (int j = 0; j < 16; ++j) {
    const int i = t * 16 + j;
    float4 p = bp[i];
    x[j] = p.x; y[j] = p.y; z[j] = p.z;
    m[j] = (i < len) ? __builtin_inff() : -__builtin_inff();
  }

  float4 c0 = bp[0];  // reference scan starts at cur=0
  float cx = c0.x, cy = c0.y, cz = c0.z;
  if (t == 0) {
    size_t o = (size_t)b * NG * 3;
    centers[o] = cx; centers[o + 1] = cy; centers[o + 2] = cz;
  }

  for (int k = 0; k < NG - 1; ++k) {
    // --- mindist update (exact per-point formula, contract OFF) ---
#pragma unroll
    for (int j = 0; j < 16; ++j) {
      float dx = x[j] - cx;
      float dy = y[j] - cy;
      float dz = z[j] - cz;
      float d = dx * dx + dy * dy + dz * dz;  // ((dx2+dy2)+dz2), matches np.sum
      m[j] = fminf(m[j], d);
    }
    // --- per-thread max via tree (fuses to v_max3) ---
    float a0 = fmaxf(m[0], m[1]),  a1 = fmaxf(m[2], m[3]);
    float a2 = fmaxf(m[4], m[5]),  a3 = fmaxf(m[6], m[7]);
    float a4 = fmaxf(m[8], m[9]),  a5 = fmaxf(m[10], m[11]);
    float a6 = fmaxf(m[12], m[13]), a7 = fmaxf(m[14], m[15]);
    float b0 = fmaxf(a0, a1), b1 = fmaxf(a2, a3);
    float b2 = fmaxf(a4, a5), b3 = fmaxf(a6, a7);
    const float bd = fmaxf(fmaxf(b0, b1), fmaxf(b2, b3));

    // --- every lane extracts its own argmax coords (first j, cndmask chain;
    //     overlaps the shuffle-reduce below, no runtime register indexing) ---
    float gx = x[0], gy = y[0], gz = z[0];
    bool fnd = (m[0] == bd);
#pragma unroll
    for (int j = 1; j < 16; ++j) {
      const bool sel = (m[j] == bd) && !fnd;
      gx = sel ? x[j] : gx;
      gy = sel ? y[j] : gy;
      gz = sel ? z[j] : gz;
      fnd = fnd || sel;
    }

    // --- wave max (f32, 6 steps) + first-lane tie-break ---
    float wmax = bd;
#pragma unroll
    for (int off = 32; off; off >>= 1) wmax = fmaxf(wmax, __shfl_xor(wmax, off, 64));
    const unsigned long long eqm = __ballot(bd == wmax);
    const int wl = __ffsll(eqm) - 1;  // lowest lane == lowest index in wave

    // --- winner lane publishes {coords, wavemax} in one b128 ---
    if (lane == wl) s_pub[k & 1][t >> 6] = make_float4(gx, gy, gz, wmax);
    __syncthreads();

    // --- all waves redundantly reduce the 16 wave maxima ---
    float4 pub = s_pub[k & 1][lane & 15];
    float kmax = pub.w;
#pragma unroll
    for (int off = 8; off; off >>= 1) kmax = fmaxf(kmax, __shfl_xor(kmax, off, 64));
    const unsigned long long bm = __ballot(pub.w == kmax);
    const unsigned gm = (unsigned)((bm >> (lane & 48)) & 0xFFFFull);
    const int winw = __ffs(gm) - 1;  // lowest wave == lowest index globally
    cx = __shfl(pub.x, winw, 64);    // groups replicate lanes 0-15; uniform result
    cy = __shfl(pub.y, winw, 64);
    cz = __shfl(pub.z, winw, 64);

    if (t == 0) {
      size_t o = ((size_t)b * NG + (k + 1)) * 3;
      centers[o] = cx; centers[o + 1] = cy; centers[o + 2] = cz;
    }
  }
}

// ---------------- Kernel 2: ball query + energy top-k + gather ----------------
// One wave per (batch, group). Ordered compaction of first 160 in-ball indices,
// then 32 rounds of min-key extraction = top_k by (energy desc, index asc).
__global__ __launch_bounds__(64) void group_kernel(const float4* __restrict__ p4,
                                                   const int* __restrict__ lengths,
                                                   const float* __restrict__ centers,
                                                   float4* __restrict__ outg) {
#pragma clang fp contract(off)
  const int gid = blockIdx.x;
  const int b = gid >> 9;
  const int lane = threadIdx.x;
  const int len = lengths[b];
  const float4* bp = p4 + (size_t)b * N_;
  const float cx = centers[(size_t)gid * 3 + 0];
  const float cy = centers[(size_t)gid * 3 + 1];
  const float cz = centers[(size_t)gid * 3 + 2];

  __shared__ int cand[KORIG];
  int M = 0;  // wave-uniform running in-ball count
  for (int cb = 0; cb < N_ && M < KORIG; cb += 256) {
#pragma unroll
    for (int q = 0; q < 4; ++q) {
      const int i = cb + q * 64 + lane;
      float4 p = bp[i];
      float dx = p.x - cx;
      float dy = p.y - cy;
      float dz = p.z - cz;
      float d2 = dx * dx + dy * dy + dz * dz;  // contract OFF
      const bool pred = (i < len) && (d2 < R2);
      unsigned long long mb = __ballot(pred);
      if (pred) {
        int pos = M + (int)__popcll(mb & ((1ull << lane) - 1ull));
        if (pos < KORIG) cand[pos] = i;  // first-160-by-index semantics
      }
      M += (int)__popcll(mb);
    }
  }
  if (M > KORIG) M = KORIG;
  __syncthreads();

  // keys: (energy desc, index asc) -> ascending u64
  const unsigned long long SENT = ~0ull;
  unsigned long long key0 = SENT, key1 = SENT, key2 = SENT;
  {
    int c0 = lane, c1 = lane + 64, c2 = lane + 128;
    if (c0 < M) { int i = cand[c0]; key0 = ((unsigned long long)(~f32_ord(bp[i].w)) << 32) | (unsigned)i; }
    if (c1 < M) { int i = cand[c1]; key1 = ((unsigned long long)(~f32_ord(bp[i].w)) << 32) | (unsigned)i; }
    if (c2 < M) { int i = cand[c2]; key2 = ((unsigned long long)(~f32_ord(bp[i].w)) << 32) | (unsigned)i; }
  }

  int mysel = -1;  // lane j holds the j-th selected index
  for (int j = 0; j < GS; ++j) {
    unsigned long long kmin = key0 < key1 ? key0 : key1;
    if (key2 < kmin) kmin = key2;
#pragma unroll
    for (int off = 32; off > 0; off >>= 1) {
      unsigned long long o = __shfl_xor(kmin, off, 64);
      if (o < kmin) kmin = o;
    }
    if (kmin == SENT) break;  // fewer than 32 candidates; rest stay -1
    if (lane == j) mysel = (int)(unsigned)kmin;
    if (key0 == kmin) key0 = SENT;
    if (key1 == kmin) key1 = SENT;
    if (key2 == kmin) key2 = SENT;
  }

  const int first = __shfl(mysel, 0, 64);  // highest-energy candidate (or -1 if empty)
  if (lane < GS) {
    int idx = (mysel < 0) ? first : mysel;  // reference: -1 -> idx[:, :, :1]
    float4 o;
    if (idx >= 0) {
      float4 p = bp[idx];
      o.x = (p.x - cx) / RADIUS;
      o.y = (p.y - cy) / RADIUS;
      o.z = (p.z - cz) / RADIUS;
      o.w = p.w / RADIUS;
    } else {
      // masked_gather gives 0, then (0 - center)/radius
      o.x = (0.0f - cx) / RADIUS;
      o.y = (0.0f - cy) / RADIUS;
      o.z = (0.0f - cz) / RADIUS;
      o.w = 0.0f;
    }
    outg[(size_t)gid * GS + lane] = o;
  }
}

extern "C" void kernel_launch(void* const* d_in, const int* in_sizes, int n_in,
                              void* d_out, int out_size, void* d_ws, size_t ws_size,
                              hipStream_t stream) {
  const float4* pts = (const float4*)d_in[0];
  const int* lengths = (const int*)d_in[1];
  float* out = (float*)d_out;
  // out layout: groups (8,512,32,4) flat, then centers (8,512,3) flat
  float* centers = out + (size_t)B_ * NG * GS * 4;
  float4* groups = (float4*)out;

  fps_kernel<<<B_, 1024, 0, stream>>>(pts, lengths, centers);
  group_kernel<<<B_ * NG, 64, 0, stream>>>(pts, lengths, centers, groups);
}

// Round 4
// 1109.885 us; speedup vs baseline: 1.2715x; 1.0774x over previous
//
#include <hip/hip_runtime.h>

// Problem constants (from reference)
constexpr int B_ = 8;
constexpr int N_ = 16384;
constexpr int NG = 512;     // NUM_GROUPS
constexpr int GS = 32;      // GROUP_SIZE
constexpr int KORIG = 160;  // K_ORIGINAL = 5*GROUP_SIZE
#define R2 0.04f
#define RADIUS 0.2f
#define PADF 2e-3f          // prune-certificate slack; >> f32 rounding of the chain

__device__ __forceinline__ unsigned f32_ord(float f) {
  unsigned u = __float_as_uint(f);
  return (u & 0x80000000u) ? ~u : (u | 0x80000000u);
}

__device__ __forceinline__ unsigned spread4(unsigned b) {
  return (b & 1u) | ((b & 2u) << 2) | ((b & 4u) << 4) | ((b & 8u) << 6);
}
__device__ __forceinline__ unsigned q4(float v) {
  int qi = (int)((v + 4.0f) * 2.0f);   // 16 cells over [-4,4]
  qi = qi < 0 ? 0 : (qi > 15 ? 15 : qi);
  return (unsigned)qi;
}
__device__ __forceinline__ int morton12(float x, float y, float z) {
  return (int)(spread4(q4(x)) | (spread4(q4(y)) << 1) | (spread4(q4(z)) << 2));
}

// ---------------- Kernel 1: Morton-grouped, sphere-pruned exact FPS ----------------
// One block per batch, 1024 threads. Prologue: 12-bit Morton counting sort so each
// thread owns 16 spatially-compact points. Main loop: thread skips its update when
// dist(center, centroid) >= R_g + sqrt(sm) + PAD  (then every fmin is provably a
// no-op => m[] stays bit-exact). Reduce uses packed (ord(dist), inv orig idx) keys
// => global argmax with first-original-index tie-break, permutation-independent.
__global__ __launch_bounds__(1024) void fps_kernel(const float4* __restrict__ p4,
                                                   const int* __restrict__ lengths,
                                                   float* __restrict__ centers) {
#pragma clang fp contract(off)
  const int b = blockIdx.x;
  const int t = threadIdx.x;
  const int lane = t & 63;
  const int wid = t >> 6;
  const int len = lengths[b];
  const float4* bp = p4 + (size_t)b * N_;
  const float NINF = -__builtin_inff();

  __shared__ unsigned hist[4096];
  __shared__ unsigned short sidx[N_];
  __shared__ unsigned long long pub[2][16];
  __shared__ unsigned wsum[16];

  // ---- prologue: counting sort by 12-bit Morton ----
  hist[t * 4 + 0] = 0; hist[t * 4 + 1] = 0; hist[t * 4 + 2] = 0; hist[t * 4 + 3] = 0;
  __syncthreads();

  int bin_r[16];
#pragma unroll
  for (int j = 0; j < 16; ++j) {
    const int i = t + j * 1024;  // coalesced
    float4 p = bp[i];
    bin_r[j] = morton12(p.x, p.y, p.z);
    atomicAdd(&hist[bin_r[j]], 1u);
  }
  __syncthreads();

  // block exclusive prefix over 4096 counters (4 per thread)
  unsigned h0 = hist[t * 4 + 0], h1 = hist[t * 4 + 1], h2 = hist[t * 4 + 2], h3 = hist[t * 4 + 3];
  unsigned s = h0 + h1 + h2 + h3;
  unsigned incl = s;
#pragma unroll
  for (int d = 1; d < 64; d <<= 1) {
    unsigned v = __shfl_up(incl, d, 64);
    if (lane >= d) incl += v;
  }
  if (lane == 63) wsum[wid] = incl;
  __syncthreads();
  unsigned woff = 0;
#pragma unroll
  for (int w = 0; w < 16; ++w) woff += (w < wid) ? wsum[w] : 0u;
  const unsigned excl = woff + incl - s;
  __syncthreads();  // all reads of hist done before cursor overwrite
  hist[t * 4 + 0] = excl;
  hist[t * 4 + 1] = excl + h0;
  hist[t * 4 + 2] = excl + h0 + h1;
  hist[t * 4 + 3] = excl + h0 + h1 + h2;
  __syncthreads();

#pragma unroll
  for (int j = 0; j < 16; ++j) {
    const int i = t + j * 1024;
    unsigned pos = atomicAdd(&hist[bin_r[j]], 1u);  // scatter order arbitrary: FPS is
    sidx[pos] = (unsigned short)i;                  // permutation-independent (exact keys)
  }
  __syncthreads();

  // ---- gather my 16 spatially-compact points ----
  float x[16], y[16], z[16], m[16];
  int iidx[16];
#pragma unroll
  for (int j = 0; j < 16; ++j) {
    const int si = (int)sidx[t * 16 + j];
    float4 p = bp[si];
    x[j] = p.x; y[j] = p.y; z[j] = p.z;
    iidx[j] = si;
    m[j] = (si < len) ? __builtin_inff() : NINF;
  }
  // centroid + bounding radius (approximation quality only affects prune rate)
  float gcx = 0.f, gcy = 0.f, gcz = 0.f;
#pragma unroll
  for (int j = 0; j < 16; ++j) { gcx += x[j]; gcy += y[j]; gcz += z[j]; }
  gcx *= 0.0625f; gcy *= 0.0625f; gcz *= 0.0625f;
  float r2max = 0.f;
#pragma unroll
  for (int j = 0; j < 16; ++j) {
    float dx = x[j] - gcx, dy = y[j] - gcy, dz = z[j] - gcz;
    r2max = fmaxf(r2max, dx * dx + dy * dy + dz * dz);
  }
  const float Rg = sqrtf(r2max) + 1e-3f;

  float sm = NINF;
#pragma unroll
  for (int j = 0; j < 16; ++j) sm = fmaxf(sm, m[j]);
  int argidx = 16383;
  // k=0: valid threads must be active (m=+inf needs real distances); all-invalid prune forever
  float thrsq = (sm == NINF) ? NINF : __builtin_inff();

  float4 c0 = bp[0];  // reference scan starts at cur=0
  float cx = c0.x, cy = c0.y, cz = c0.z;
  if (t == 0) {
    size_t o = (size_t)b * NG * 3;
    centers[o] = cx; centers[o + 1] = cy; centers[o + 2] = cz;
  }

  for (int k = 0; k < NG - 1; ++k) {
    // --- sphere prune certificate ---
    float dcx = cx - gcx, dcy = cy - gcy, dcz = cz - gcz;
    float dc2 = dcx * dcx + dcy * dcy + dcz * dcz;
    const bool active = !(dc2 >= thrsq);
    if (__any(active)) {
      if (active) {
        // exact eager update (bit-identical to reference per (point,center) pair)
#pragma unroll
        for (int j = 0; j < 16; ++j) {
          float dx = x[j] - cx;
          float dy = y[j] - cy;
          float dz = z[j] - cz;
          float d = dx * dx + dy * dy + dz * dz;  // contract OFF
          m[j] = fminf(m[j], d);
        }
        // thread max (v_max3-friendly)
        float t0 = fmaxf(fmaxf(m[0], m[1]), m[2]);
        float t1 = fmaxf(fmaxf(m[3], m[4]), m[5]);
        float t2 = fmaxf(fmaxf(m[6], m[7]), m[8]);
        float t3 = fmaxf(fmaxf(m[9], m[10]), m[11]);
        float t4 = fmaxf(fmaxf(m[12], m[13]), m[14]);
        float u0 = fmaxf(fmaxf(t0, t1), t2);
        float u1 = fmaxf(fmaxf(t3, t4), m[15]);
        sm = fmaxf(u0, u1);
        // first-original-index among per-thread maxima
        unsigned a0 = (m[0] == sm) ? (unsigned)iidx[0] : 0xFFFFu;
        unsigned a1 = (m[1] == sm) ? (unsigned)iidx[1] : 0xFFFFu;
        unsigned a2 = (m[2] == sm) ? (unsigned)iidx[2] : 0xFFFFu;
        unsigned a3 = (m[3] == sm) ? (unsigned)iidx[3] : 0xFFFFu;
        unsigned a4 = (m[4] == sm) ? (unsigned)iidx[4] : 0xFFFFu;
        unsigned a5 = (m[5] == sm) ? (unsigned)iidx[5] : 0xFFFFu;
        unsigned a6 = (m[6] == sm) ? (unsigned)iidx[6] : 0xFFFFu;
        unsigned a7 = (m[7] == sm) ? (unsigned)iidx[7] : 0xFFFFu;
        unsigned a8 = (m[8] == sm) ? (unsigned)iidx[8] : 0xFFFFu;
        unsigned a9 = (m[9] == sm) ? (unsigned)iidx[9] : 0xFFFFu;
        unsigned aA = (m[10] == sm) ? (unsigned)iidx[10] : 0xFFFFu;
        unsigned aB = (m[11] == sm) ? (unsigned)iidx[11] : 0xFFFFu;
        unsigned aC = (m[12] == sm) ? (unsigned)iidx[12] : 0xFFFFu;
        unsigned aD = (m[13] == sm) ? (unsigned)iidx[13] : 0xFFFFu;
        unsigned aE = (m[14] == sm) ? (unsigned)iidx[14] : 0xFFFFu;
        unsigned aF = (m[15] == sm) ? (unsigned)iidx[15] : 0xFFFFu;
        unsigned b0 = min(min(a0, a1), min(a2, a3));
        unsigned b1 = min(min(a4, a5), min(a6, a7));
        unsigned b2 = min(min(a8, a9), min(aA, aB));
        unsigned b3 = min(min(aC, aD), min(aE, aF));
        argidx = (int)min(min(b0, b1), min(b2, b3));
        // refresh prune threshold (PAD absorbs all f32 rounding in the certificate)
        float thr = Rg + sqrtf(sm) + PADF;
        thrsq = (sm == NINF) ? NINF : thr * thr;
      }
    }
    // --- exact global argmax: packed (ord(sm), 16383-argidx), max-reduce ---
    unsigned long long key =
        ((unsigned long long)f32_ord(sm) << 14) | (unsigned long long)(16383 - argidx);
#pragma unroll
    for (int off = 32; off; off >>= 1) {
      unsigned long long o = __shfl_xor(key, off, 64);
      if (o > key) key = o;
    }
    if (lane == 0) pub[k & 1][wid] = key;
    __syncthreads();
    unsigned long long kk = pub[k & 1][lane & 15];
#pragma unroll
    for (int off = 8; off; off >>= 1) {
      unsigned long long o = __shfl_xor(kk, off, 64);
      if (o > kk) kk = o;
    }
    const int nxt = 16383 - (int)(kk & 0x3FFFull);
    float4 c = bp[nxt];  // uniform address, L2-hot
    cx = c.x; cy = c.y; cz = c.z;
    if (t == 0) {
      size_t o = ((size_t)b * NG + (k + 1)) * 3;
      centers[o] = cx; centers[o + 1] = cy; centers[o + 2] = cz;
    }
  }
}

// ---------------- Kernel 2: ball query + energy top-k + gather ----------------
// One wave per (batch, group). Ordered compaction of first 160 in-ball indices,
// then 32 rounds of min-key extraction = top_k by (energy desc, index asc).
__global__ __launch_bounds__(64) void group_kernel(const float4* __restrict__ p4,
                                                   const int* __restrict__ lengths,
                                                   const float* __restrict__ centers,
                                                   float4* __restrict__ outg) {
#pragma clang fp contract(off)
  const int gid = blockIdx.x;
  const int b = gid >> 9;
  const int lane = threadIdx.x;
  const int len = lengths[b];
  const float4* bp = p4 + (size_t)b * N_;
  const float cx = centers[(size_t)gid * 3 + 0];
  const float cy = centers[(size_t)gid * 3 + 1];
  const float cz = centers[(size_t)gid * 3 + 2];

  __shared__ int cand[KORIG];
  int M = 0;  // wave-uniform running in-ball count
  for (int cb = 0; cb < N_ && M < KORIG; cb += 256) {
#pragma unroll
    for (int q = 0; q < 4; ++q) {
      const int i = cb + q * 64 + lane;
      float4 p = bp[i];
      float dx = p.x - cx;
      float dy = p.y - cy;
      float dz = p.z - cz;
      float d2 = dx * dx + dy * dy + dz * dz;  // contract OFF
      const bool pred = (i < len) && (d2 < R2);
      unsigned long long mb = __ballot(pred);
      if (pred) {
        int pos = M + (int)__popcll(mb & ((1ull << lane) - 1ull));
        if (pos < KORIG) cand[pos] = i;  // first-160-by-index semantics
      }
      M += (int)__popcll(mb);
    }
  }
  if (M > KORIG) M = KORIG;
  __syncthreads();

  // keys: (energy desc, index asc) -> ascending u64
  const unsigned long long SENT = ~0ull;
  unsigned long long key0 = SENT, key1 = SENT, key2 = SENT;
  {
    int c0 = lane, c1 = lane + 64, c2 = lane + 128;
    if (c0 < M) { int i = cand[c0]; key0 = ((unsigned long long)(~f32_ord(bp[i].w)) << 32) | (unsigned)i; }
    if (c1 < M) { int i = cand[c1]; key1 = ((unsigned long long)(~f32_ord(bp[i].w)) << 32) | (unsigned)i; }
    if (c2 < M) { int i = cand[c2]; key2 = ((unsigned long long)(~f32_ord(bp[i].w)) << 32) | (unsigned)i; }
  }

  int mysel = -1;  // lane j holds the j-th selected index
  for (int j = 0; j < GS; ++j) {
    unsigned long long kmin = key0 < key1 ? key0 : key1;
    if (key2 < kmin) kmin = key2;
#pragma unroll
    for (int off = 32; off > 0; off >>= 1) {
      unsigned long long o = __shfl_xor(kmin, off, 64);
      if (o < kmin) kmin = o;
    }
    if (kmin == SENT) break;  // fewer than 32 candidates; rest stay -1
    if (lane == j) mysel = (int)(unsigned)kmin;
    if (key0 == kmin) key0 = SENT;
    if (key1 == kmin) key1 = SENT;
    if (key2 == kmin) key2 = SENT;
  }

  const int first = __shfl(mysel, 0, 64);  // highest-energy candidate (or -1 if empty)
  if (lane < GS) {
    int idx = (mysel < 0) ? first : mysel;  // reference: -1 -> idx[:, :, :1]
    float4 o;
    if (idx >= 0) {
      float4 p = bp[idx];
      o.x = (p.x - cx) / RADIUS;
      o.y = (p.y - cy) / RADIUS;
      o.z = (p.z - cz) / RADIUS;
      o.w = p.w / RADIUS;
    } else {
      // masked_gather gives 0, then (0 - center)/radius
      o.x = (0.0f - cx) / RADIUS;
      o.y = (0.0f - cy) / RADIUS;
      o.z = (0.0f - cz) / RADIUS;
      o.w = 0.0f;
    }
    outg[(size_t)gid * GS + lane] = o;
  }
}

extern "C" void kernel_launch(void* const* d_in, const int* in_sizes, int n_in,
                              void* d_out, int out_size, void* d_ws, size_t ws_size,
                              hipStream_t stream) {
  const float4* pts = (const float4*)d_in[0];
  const int* lengths = (const int*)d_in[1];
  float* out = (float*)d_out;
  // out layout: groups (8,512,32,4) flat, then centers (8,512,3) flat
  float* centers = out + (size_t)B_ * NG * GS * 4;
  float4* groups = (float4*)out;

  fps_kernel<<<B_, 1024, 0, stream>>>(pts, lengths, centers);
  group_kernel<<<B_ * NG, 64, 0, stream>>>(pts, lengths, centers, groups);
}

// Round 6
// 1002.625 us; speedup vs baseline: 1.4075x; 1.1070x over previous
//
#include <hip/hip_runtime.h>

// Problem constants (from reference)
constexpr int B_ = 8;
constexpr int N_ = 16384;
constexpr int NG = 512;     // NUM_GROUPS
constexpr int GS = 32;      // GROUP_SIZE
constexpr int KORIG = 160;  // K_ORIGINAL = 5*GROUP_SIZE
constexpr int TPB = 512;    // fps threads (8 waves)
constexpr int PPT = 32;     // points per thread, contiguous
#define R2 0.04f
#define RADIUS 0.2f

__device__ __forceinline__ unsigned f32_ord(float f) {
  unsigned u = __float_as_uint(f);
  return (u & 0x80000000u) ? ~u : (u | 0x80000000u);
}

// fmax with a DPP-permuted copy; ctrl must be an immediate -> template param
template <int CTRL>
__device__ __forceinline__ float dpp_fmax(float v) {
  int o = __builtin_amdgcn_update_dpp(0, __float_as_int(v), CTRL, 0xF, 0xF, true);
  return fmaxf(v, __int_as_float(o));
}
// full 64-lane max: xor1,xor2 (quad_perm), mirrors within 8/16, xor16, xor32
__device__ __forceinline__ float wave_fmax(float v) {
  v = dpp_fmax<0xB1>(v);   // quad_perm [1,0,3,2]
  v = dpp_fmax<0x4E>(v);   // quad_perm [2,3,0,1]
  v = dpp_fmax<0x141>(v);  // row_half_mirror (combines quads within 8)
  v = dpp_fmax<0x140>(v);  // row_mirror      (combines 8s within 16)
  v = fmaxf(v, __int_as_float(__builtin_amdgcn_ds_swizzle(__float_as_int(v), 0x401F)));  // xor16
  v = fmaxf(v, __shfl_xor(v, 32, 64));  // xor32
  return v;
}
// max within each 8-lane group (lanes 8g..8g+7 hold the 8 wave partials)
__device__ __forceinline__ float group8_fmax(float v) {
  v = dpp_fmax<0xB1>(v);
  v = dpp_fmax<0x4E>(v);
  v = dpp_fmax<0x141>(v);
  return v;
}

// ---------------- Kernel 1: farthest point sampling ----------------
// One block per batch, 512 threads (8 waves), thread t owns points [32t,32t+32)
// CONTIGUOUS: global index order == (wave, lane, j) order, so first-index
// argmax tie-break = lowest wave, lowest lane, lowest j — no index keys needed.
// One barrier/iter; f32 DPP reduces; speculative candidate gather overlaps the
// cross-wave reduce so the winner-coords load is off the critical path.
__global__ __launch_bounds__(512) void fps_kernel(const float4* __restrict__ p4,
                                                  const int* __restrict__ lengths,
                                                  float* __restrict__ centers) {
#pragma clang fp contract(off)
  const int b = blockIdx.x;
  const int t = threadIdx.x;
  const int lane = t & 63;
  const int wid = t >> 6;
  const int len = lengths[b];
  const float4* bp = p4 + (size_t)b * N_;

  __shared__ unsigned long long pub[2][8];  // {f32 wavemax, u32 idx}, parity dbuf

  float x[PPT], y[PPT], z[PPT], m[PPT];
#pragma unroll
  for (int j = 0; j < PPT; ++j) {
    const int i = t * PPT + j;
    float4 p = bp[i];
    x[j] = p.x; y[j] = p.y; z[j] = p.z;
    m[j] = (i < len) ? __builtin_inff() : -__builtin_inff();
  }

  float4 c0 = bp[0];  // reference scan starts at cur=0
  float cx = c0.x, cy = c0.y, cz = c0.z;
  if (t == 0) {
    size_t o = (size_t)b * NG * 3;
    centers[o] = cx; centers[o + 1] = cy; centers[o + 2] = cz;
  }

  for (int k = 0; k < NG - 1; ++k) {
    // --- mindist update: exact per-point formula (contract OFF) ---
#pragma unroll
    for (int j = 0; j < PPT; ++j) {
      float dx = x[j] - cx;
      float dy = y[j] - cy;
      float dz = z[j] - cz;
      float d = dx * dx + dy * dy + dz * dz;  // ((dx2+dy2)+dz2) = np.sum order
      m[j] = fminf(m[j], d);
    }
    // --- thread max: 31-op pairwise tree (v_max3-fusable) ---
    float u0 = fmaxf(m[0], m[1]),   u1 = fmaxf(m[2], m[3]);
    float u2 = fmaxf(m[4], m[5]),   u3 = fmaxf(m[6], m[7]);
    float u4 = fmaxf(m[8], m[9]),   u5 = fmaxf(m[10], m[11]);
    float u6 = fmaxf(m[12], m[13]), u7 = fmaxf(m[14], m[15]);
    float u8 = fmaxf(m[16], m[17]), u9 = fmaxf(m[18], m[19]);
    float uA = fmaxf(m[20], m[21]), uB = fmaxf(m[22], m[23]);
    float uC = fmaxf(m[24], m[25]), uD = fmaxf(m[26], m[27]);
    float uE = fmaxf(m[28], m[29]), uF = fmaxf(m[30], m[31]);
    float v0 = fmaxf(u0, u1), v1 = fmaxf(u2, u3), v2 = fmaxf(u4, u5), v3 = fmaxf(u6, u7);
    float v4 = fmaxf(u8, u9), v5 = fmaxf(uA, uB), v6 = fmaxf(uC, uD), v7 = fmaxf(uE, uF);
    float w0 = fmaxf(v0, v1), w1 = fmaxf(v2, v3), w2 = fmaxf(v4, v5), w3 = fmaxf(v6, v7);
    const float sm = fmaxf(fmaxf(w0, w1), fmaxf(w2, w3));
    // --- first attaining j (j order == original index order) ---
    int bj = 31;
#pragma unroll
    for (int j = 30; j >= 0; --j) bj = (m[j] == sm) ? j : bj;

    // --- wave max (DPP) + first-lane tie-break ---
    const float wmax = wave_fmax(sm);
    const unsigned long long att = __ballot(sm == wmax);
    const int wl = __ffsll((unsigned long long)att) - 1;  // lowest lane = lowest index
    if (lane == wl) {
      pub[k & 1][wid] = ((unsigned long long)__float_as_uint(wmax) << 32) |
                        (unsigned)(t * PPT + bj);
    }
    __syncthreads();

    // --- cross-wave: read 8 partials, speculative-gather candidates, reduce ---
    const unsigned long long pv = pub[k & 1][lane & 7];
    const float pw = __uint_as_float((unsigned)(pv >> 32));
    const int pi = (int)(unsigned)(pv & 0xFFFFFFFFull);
    const float4 pc = bp[pi];  // candidates gather; latency hides under reduce
    const float kmax = group8_fmax(pw);
    const unsigned long long bal = __ballot(pw == kmax);
    const int grp = lane & 56;
    const int winw = grp + (__ffsll((bal >> grp) & 0xFFull) - 1);  // lowest wave wins
    cx = __shfl(pc.x, winw, 64);
    cy = __shfl(pc.y, winw, 64);
    cz = __shfl(pc.z, winw, 64);

    if (t == 0) {
      size_t o = ((size_t)b * NG + (k + 1)) * 3;
      centers[o] = cx; centers[o + 1] = cy; centers[o + 2] = cz;
    }
  }
}

// ---------------- Kernel 2: ball query + energy top-k + gather ----------------
// One wave per (batch, group). Ordered compaction of first 160 in-ball indices,
// then 32 rounds of min-key extraction = top_k by (energy desc, index asc).
__global__ __launch_bounds__(64) void group_kernel(const float4* __restrict__ p4,
                                                   const int* __restrict__ lengths,
                                                   const float* __restrict__ centers,
                                                   float4* __restrict__ outg) {
#pragma clang fp contract(off)
  const int gid = blockIdx.x;
  const int b = gid >> 9;
  const int lane = threadIdx.x;
  const int len = lengths[b];
  const float4* bp = p4 + (size_t)b * N_;
  const float cx = centers[(size_t)gid * 3 + 0];
  const float cy = centers[(size_t)gid * 3 + 1];
  const float cz = centers[(size_t)gid * 3 + 2];

  __shared__ int cand[KORIG];
  int M = 0;  // wave-uniform running in-ball count
  for (int cb = 0; cb < N_ && M < KORIG; cb += 256) {
#pragma unroll
    for (int q = 0; q < 4; ++q) {
      const int i = cb + q * 64 + lane;
      float4 p = bp[i];
      float dx = p.x - cx;
      float dy = p.y - cy;
      float dz = p.z - cz;
      float d2 = dx * dx + dy * dy + dz * dz;  // contract OFF
      const bool pred = (i < len) && (d2 < R2);
      unsigned long long mb = __ballot(pred);
      if (pred) {
        int pos = M + (int)__popcll(mb & ((1ull << lane) - 1ull));
        if (pos < KORIG) cand[pos] = i;  // first-160-by-index semantics
      }
      M += (int)__popcll(mb);
    }
  }
  if (M > KORIG) M = KORIG;
  __syncthreads();

  // keys: (energy desc, index asc) -> ascending u64
  const unsigned long long SENT = ~0ull;
  unsigned long long key0 = SENT, key1 = SENT, key2 = SENT;
  {
    int c0 = lane, c1 = lane + 64, c2 = lane + 128;
    if (c0 < M) { int i = cand[c0]; key0 = ((unsigned long long)(~f32_ord(bp[i].w)) << 32) | (unsigned)i; }
    if (c1 < M) { int i = cand[c1]; key1 = ((unsigned long long)(~f32_ord(bp[i].w)) << 32) | (unsigned)i; }
    if (c2 < M) { int i = cand[c2]; key2 = ((unsigned long long)(~f32_ord(bp[i].w)) << 32) | (unsigned)i; }
  }

  int mysel = -1;  // lane j holds the j-th selected index
  for (int j = 0; j < GS; ++j) {
    unsigned long long kmin = key0 < key1 ? key0 : key1;
    if (key2 < kmin) kmin = key2;
#pragma unroll
    for (int off = 32; off > 0; off >>= 1) {
      unsigned long long o = __shfl_xor(kmin, off, 64);
      if (o < kmin) kmin = o;
    }
    if (kmin == SENT) break;  // fewer than 32 candidates; rest stay -1
    if (lane == j) mysel = (int)(unsigned)kmin;
    if (key0 == kmin) key0 = SENT;
    if (key1 == kmin) key1 = SENT;
    if (key2 == kmin) key2 = SENT;
  }

  const int first = __shfl(mysel, 0, 64);  // highest-energy candidate (or -1 if empty)
  if (lane < GS) {
    int idx = (mysel < 0) ? first : mysel;  // reference: -1 -> idx[:, :, :1]
    float4 o;
    if (idx >= 0) {
      float4 p = bp[idx];
      o.x = (p.x - cx) / RADIUS;
      o.y = (p.y - cy) / RADIUS;
      o.z = (p.z - cz) / RADIUS;
      o.w = p.w / RADIUS;
    } else {
      // masked_gather gives 0, then (0 - center)/radius
      o.x = (0.0f - cx) / RADIUS;
      o.y = (0.0f - cy) / RADIUS;
      o.z = (0.0f - cz) / RADIUS;
      o.w = 0.0f;
    }
    outg[(size_t)gid * GS + lane] = o;
  }
}

extern "C" void kernel_launch(void* const* d_in, const int* in_sizes, int n_in,
                              void* d_out, int out_size, void* d_ws, size_t ws_size,
                              hipStream_t stream) {
  const float4* pts = (const float4*)d_in[0];
  const int* lengths = (const int*)d_in[1];
  float* out = (float*)d_out;
  // out layout: groups (8,512,32,4) flat, then centers (8,512,3) flat
  float* centers = out + (size_t)B_ * NG * GS * 4;
  float4* groups = (float4*)out;

  fps_kernel<<<B_, TPB, 0, stream>>>(pts, lengths, centers);
  group_kernel<<<B_ * NG, 64, 0, stream>>>(pts, lengths, centers, groups);
}